// Round 1
// baseline (110.548 us; speedup 1.0000x reference)
//
#include <hip/hip_runtime.h>

// RoiPooling (crop_and_resize, bilinear): x (1,128,128,256) f32 NHWC,
// rois (4000,4) f32 [y1,x1,y2,x2] in [0,1] -> out (4000,7,7,256) f32.

constexpr int H = 128, W = 128, C = 256;
constexpr int PH = 7, PW = 7;
constexpr int NROI = 4000;
constexpr int NCELL = NROI * PH * PW;          // 196000 output cells
constexpr int WAVES_PER_BLOCK = 4;             // 256 threads

__global__ __launch_bounds__(256) void roi_pool_kernel(
    const float* __restrict__ x, const float* __restrict__ rois,
    float* __restrict__ out)
{
    const int wave = threadIdx.x >> 6;
    const int lane = threadIdx.x & 63;
    const int cell = blockIdx.x * WAVES_PER_BLOCK + wave;
    if (cell >= NCELL) return;

    const int r  = cell / (PH * PW);
    const int pq = cell - r * (PH * PW);
    const int iy = pq / PW;
    const int ix = pq - iy * PW;

    const float y1 = rois[r * 4 + 0];
    const float x1 = rois[r * 4 + 1];
    const float y2 = rois[r * 4 + 2];
    const float x2 = rois[r * 4 + 3];

    // Match reference order: y1*(H-1) + iy * ((y2-y1)*(H-1)/(ph-1))
    const float ys = y1 * (float)(H - 1) + (float)iy * ((y2 - y1) * (float)(H - 1) / (float)(PH - 1));
    const float xs = x1 * (float)(W - 1) + (float)ix * ((x2 - x1) * (float)(W - 1) / (float)(PW - 1));

    const float y0f = floorf(ys);
    const float x0f = floorf(xs);
    const float wy = ys - y0f;
    const float wx = xs - x0f;

    int y0  = (int)y0f; y0  = min(max(y0, 0), H - 1);
    int y1i = min(y0 + 1, H - 1);
    int x0  = (int)x0f; x0  = min(max(x0, 0), W - 1);
    int x1i = min(x0 + 1, W - 1);

    const bool valid = (ys >= 0.0f) & (ys <= (float)(H - 1)) &
                       (xs >= 0.0f) & (xs <= (float)(W - 1));

    // Each lane handles 4 contiguous channels.
    const int c4 = lane;  // float4 index within the 256-channel row
    const float4* p00 = (const float4*)(x + ((long)y0  * W + x0 ) * C);
    const float4* p01 = (const float4*)(x + ((long)y0  * W + x1i) * C);
    const float4* p10 = (const float4*)(x + ((long)y1i * W + x0 ) * C);
    const float4* p11 = (const float4*)(x + ((long)y1i * W + x1i) * C);

    const float4 a = p00[c4];
    const float4 b = p01[c4];
    const float4 c = p10[c4];
    const float4 d = p11[c4];

    float4 res;
    {
        const float t0 = a.x * (1.0f - wx) + b.x * wx;
        const float b0 = c.x * (1.0f - wx) + d.x * wx;
        res.x = t0 * (1.0f - wy) + b0 * wy;
        const float t1 = a.y * (1.0f - wx) + b.y * wx;
        const float b1 = c.y * (1.0f - wx) + d.y * wx;
        res.y = t1 * (1.0f - wy) + b1 * wy;
        const float t2 = a.z * (1.0f - wx) + b.z * wx;
        const float b2 = c.z * (1.0f - wx) + d.z * wx;
        res.z = t2 * (1.0f - wy) + b2 * wy;
        const float t3 = a.w * (1.0f - wx) + b.w * wx;
        const float b3 = c.w * (1.0f - wx) + d.w * wx;
        res.w = t3 * (1.0f - wy) + b3 * wy;
    }

    if (!valid) { res.x = 0.0f; res.y = 0.0f; res.z = 0.0f; res.w = 0.0f; }

    float4* o = (float4*)(out + (long)cell * C);
    o[c4] = res;
}

extern "C" void kernel_launch(void* const* d_in, const int* in_sizes, int n_in,
                              void* d_out, int out_size, void* d_ws, size_t ws_size,
                              hipStream_t stream)
{
    const float* x    = (const float*)d_in[0];
    const float* rois = (const float*)d_in[1];
    float* out = (float*)d_out;

    const int blocks = (NCELL + WAVES_PER_BLOCK - 1) / WAVES_PER_BLOCK;  // 49000
    roi_pool_kernel<<<blocks, 256, 0, stream>>>(x, rois, out);
}

// Round 3
// 102.849 us; speedup vs baseline: 1.0749x; 1.0749x over previous
//
#include <hip/hip_runtime.h>

// RoiPooling (crop_and_resize, bilinear): x (1,128,128,256) f32 NHWC,
// rois (4000,4) f32 [y1,x1,y2,x2] in [0,1] -> out (4000,7,7,256) f32.
//
// R3: same as R2 but with clang ext_vector_type for the nontemporal builtin
// (HIP_vector_type float4 is a class and is rejected by the builtin).

typedef float v4f __attribute__((ext_vector_type(4)));

constexpr int H = 128, W = 128, C = 256;
constexpr int PH = 7, PW = 7;
constexpr int NROI = 4000;
constexpr int NCELL = NROI * PH * PW;            // 196000 output cells
constexpr int WAVES_PER_BLOCK = 4;               // 256 threads
constexpr int CELLS_PER_WAVE = 2;
constexpr int CELLS_PER_BLOCK = WAVES_PER_BLOCK * CELLS_PER_WAVE;  // 8
// 196000 / 8 = 24500 blocks exactly, no tail.

__global__ __launch_bounds__(256) void roi_pool_kernel(
    const float* __restrict__ x, const float* __restrict__ rois,
    float* __restrict__ out)
{
    const int wave = threadIdx.x >> 6;
    const int lane = threadIdx.x & 63;
    const int cell0 = (blockIdx.x * WAVES_PER_BLOCK + wave) * CELLS_PER_WAVE;

    v4f a[CELLS_PER_WAVE], b[CELLS_PER_WAVE], c[CELLS_PER_WAVE], d[CELLS_PER_WAVE];
    float wxv[CELLS_PER_WAVE], wyv[CELLS_PER_WAVE];
    bool validv[CELLS_PER_WAVE];

#pragma unroll
    for (int k = 0; k < CELLS_PER_WAVE; ++k) {
        const int cell = cell0 + k;
        const int r  = cell / (PH * PW);
        const int pq = cell - r * (PH * PW);
        const int iy = pq / PW;
        const int ix = pq - iy * PW;

        const float y1 = rois[r * 4 + 0];
        const float x1 = rois[r * 4 + 1];
        const float y2 = rois[r * 4 + 2];
        const float x2 = rois[r * 4 + 3];

        // Match reference order exactly.
        const float ys = y1 * (float)(H - 1) + (float)iy * ((y2 - y1) * (float)(H - 1) / (float)(PH - 1));
        const float xs = x1 * (float)(W - 1) + (float)ix * ((x2 - x1) * (float)(W - 1) / (float)(PW - 1));

        const float y0f = floorf(ys);
        const float x0f = floorf(xs);
        wyv[k] = ys - y0f;
        wxv[k] = xs - x0f;

        int y0  = (int)y0f; y0  = min(max(y0, 0), H - 1);
        int y1i = min(y0 + 1, H - 1);
        int x0  = (int)x0f; x0  = min(max(x0, 0), W - 1);
        int x1i = min(x0 + 1, W - 1);

        validv[k] = (ys >= 0.0f) & (ys <= (float)(H - 1)) &
                    (xs >= 0.0f) & (xs <= (float)(W - 1));

        // 32-bit offsets are sufficient (x is 16.8MB, out is 200.7MB < 2^31).
        const unsigned base00 = ((unsigned)(y0  * W + x0 )) * C;
        const unsigned base01 = ((unsigned)(y0  * W + x1i)) * C;
        const unsigned base10 = ((unsigned)(y1i * W + x0 )) * C;
        const unsigned base11 = ((unsigned)(y1i * W + x1i)) * C;

        const unsigned c4 = (unsigned)lane * 4u;
        a[k] = *(const v4f*)(x + base00 + c4);
        b[k] = *(const v4f*)(x + base01 + c4);
        c[k] = *(const v4f*)(x + base10 + c4);
        d[k] = *(const v4f*)(x + base11 + c4);
    }

#pragma unroll
    for (int k = 0; k < CELLS_PER_WAVE; ++k) {
        const float wx = wxv[k], wy = wyv[k];
        const v4f top = a[k] * (1.0f - wx) + b[k] * wx;
        const v4f bot = c[k] * (1.0f - wx) + d[k] * wx;
        v4f res = top * (1.0f - wy) + bot * wy;
        if (!validv[k]) res = (v4f)0.0f;

        v4f* o = (v4f*)(out + (unsigned)(cell0 + k) * C + (unsigned)lane * 4u);
        __builtin_nontemporal_store(res, o);
    }
}

extern "C" void kernel_launch(void* const* d_in, const int* in_sizes, int n_in,
                              void* d_out, int out_size, void* d_ws, size_t ws_size,
                              hipStream_t stream)
{
    const float* x    = (const float*)d_in[0];
    const float* rois = (const float*)d_in[1];
    float* out = (float*)d_out;

    const int blocks = NCELL / CELLS_PER_BLOCK;  // 24500
    roi_pool_kernel<<<blocks, 256, 0, stream>>>(x, rois, out);
}